// Round 1
// baseline (6389.456 us; speedup 1.0000x reference)
//
#include <hip/hip_runtime.h>
#include <math.h>

#define NEG 0.2f

__device__ __forceinline__ float lrelu(float v) { return fmaxf(v, NEG * v); }

// K1: per-node: h1 = x@W1 (64 cols), al_src/al_dst logits, init acc1/den1 with self-loop term.
// One wave (64 lanes) per node, 4 nodes per 256-thread block. W1 staged in LDS (32 KB).
__global__ __launch_bounds__(256) void k1(const float* __restrict__ x,
        const float* __restrict__ W1, const float* __restrict__ a_src,
        const float* __restrict__ a_dst,
        float* __restrict__ h1, float* __restrict__ als, float* __restrict__ ald,
        float* __restrict__ acc1, float* __restrict__ den1, int N)
{
    __shared__ float Wl[128 * 64];
    __shared__ float xl[4][128];
    const float4* Wv = (const float4*)W1;
    float4* Wlv = (float4*)Wl;
    for (int i = threadIdx.x; i < 128 * 16; i += 256) Wlv[i] = Wv[i];

    int wave = threadIdx.x >> 6;
    int lane = threadIdx.x & 63;
    int n = blockIdx.x * 4 + wave;
    if (n < N) {
        const float4* xv = (const float4*)(x + (size_t)n * 128);
        float4* xlv = (float4*)xl[wave];
        if (lane < 32) xlv[lane] = xv[lane];
    }
    __syncthreads();
    if (n >= N) return;

    const float* xr = xl[wave];
    float sum = 0.f;
    #pragma unroll 8
    for (int k = 0; k < 128; ++k) sum = fmaf(xr[k], Wl[k * 64 + lane], sum);
    h1[(size_t)n * 64 + lane] = sum;

    float ps = sum * a_src[lane];
    float pd = sum * a_dst[lane];
    #pragma unroll
    for (int off = 1; off < 8; off <<= 1) {
        ps += __shfl_xor(ps, off, 64);
        pd += __shfl_xor(pd, off, 64);
    }
    int h = lane >> 3;
    if ((lane & 7) == 0) { als[n * 8 + h] = ps; ald[n * 8 + h] = pd; }
    // self-loop init (softmax without max-subtraction is exact)
    float w = __expf(lrelu(ps + pd));
    acc1[(size_t)n * 64 + lane] = w * sum;
    if ((lane & 7) == 0) den1[n * 8 + h] = w;
}

// K2: edge pass layer 1. One thread per (edge, head): 1 denom atomic + 8 acc atomics.
__global__ __launch_bounds__(256) void k2(const int* __restrict__ ei, int E,
        const float* __restrict__ h1, const float* __restrict__ als,
        const float* __restrict__ ald, float* __restrict__ acc1,
        float* __restrict__ den1)
{
    long long tid = (long long)blockIdx.x * 256 + threadIdx.x;
    if (tid >= (long long)E * 8) return;
    int e = (int)(tid >> 3);
    int h = (int)(tid & 7);
    int src = ei[e];
    int dst = ei[E + e];
    float w = __expf(lrelu(als[src * 8 + h] + ald[dst * 8 + h]));
    atomicAdd(&den1[dst * 8 + h], w);
    const float4* hv = (const float4*)(h1 + ((size_t)src * 64 + h * 8));
    float4 v0 = hv[0], v1 = hv[1];
    float* ab = acc1 + ((size_t)dst * 64 + h * 8);
    atomicAdd(ab + 0, w * v0.x); atomicAdd(ab + 1, w * v0.y);
    atomicAdd(ab + 2, w * v0.z); atomicAdd(ab + 3, w * v0.w);
    atomicAdd(ab + 4, w * v1.x); atomicAdd(ab + 5, w * v1.y);
    atomicAdd(ab + 6, w * v1.z); atomicAdd(ab + 7, w * v1.w);
}

// K3: normalize layer1, +b1, ReLU, dot with W2 -> h2; layer-2 logits; self-loop init of acc2/den2.
// One wave per node.
__global__ __launch_bounds__(256) void k3(const float* __restrict__ acc1,
        const float* __restrict__ den1, const float* __restrict__ b1,
        const float* __restrict__ W2, const float* __restrict__ a_src2,
        const float* __restrict__ a_dst2,
        float* __restrict__ h2, float* __restrict__ als2, float* __restrict__ ald2,
        float* __restrict__ acc2, float* __restrict__ den2, int N)
{
    int wave = threadIdx.x >> 6, lane = threadIdx.x & 63;
    int n = blockIdx.x * 4 + wave;
    if (n >= N) return;
    float v = acc1[(size_t)n * 64 + lane] / den1[n * 8 + (lane >> 3)] + b1[lane];
    v = fmaxf(v, 0.f);
    float t = v * W2[lane];
    #pragma unroll
    for (int off = 1; off < 64; off <<= 1) t += __shfl_xor(t, off, 64);
    if (lane == 0) {
        float as = t * a_src2[0], ad = t * a_dst2[0];
        h2[n] = t; als2[n] = as; ald2[n] = ad;
        float w = __expf(lrelu(as + ad));
        den2[n] = w; acc2[n] = w * t;
    }
}

// K4: edge pass layer 2. One thread per edge, 2 atomics.
__global__ __launch_bounds__(256) void k4(const int* __restrict__ ei, int E,
        const float* __restrict__ h2, const float* __restrict__ als2,
        const float* __restrict__ ald2, float* __restrict__ acc2,
        float* __restrict__ den2)
{
    int e = blockIdx.x * 256 + threadIdx.x;
    if (e >= E) return;
    int src = ei[e], dst = ei[E + e];
    float w = __expf(lrelu(als2[src] + ald2[dst]));
    atomicAdd(&den2[dst], w);
    atomicAdd(&acc2[dst], w * h2[src]);
}

// K5: final normalize + bias.
__global__ __launch_bounds__(256) void k5(const float* __restrict__ acc2,
        const float* __restrict__ den2, const float* __restrict__ b2,
        float* __restrict__ out, int N)
{
    int n = blockIdx.x * 256 + threadIdx.x;
    if (n < N) out[n] = acc2[n] / den2[n] + b2[0];
}

extern "C" void kernel_launch(void* const* d_in, const int* in_sizes, int n_in,
                              void* d_out, int out_size, void* d_ws, size_t ws_size,
                              hipStream_t stream)
{
    const float* x   = (const float*)d_in[0];
    const float* W1  = (const float*)d_in[1];
    const float* as1 = (const float*)d_in[2];
    const float* ad1 = (const float*)d_in[3];
    const float* b1  = (const float*)d_in[4];
    const float* W2  = (const float*)d_in[5];
    const float* as2 = (const float*)d_in[6];
    const float* ad2 = (const float*)d_in[7];
    const float* b2  = (const float*)d_in[8];
    const int*   ei  = (const int*)d_in[9];

    int N = in_sizes[0] / 128;
    int E = in_sizes[9] / 2;

    float* ws   = (float*)d_ws;
    float* h1   = ws;                       // N*64
    float* als  = h1   + (size_t)N * 64;    // N*8
    float* ald  = als  + (size_t)N * 8;     // N*8
    float* acc1 = ald  + (size_t)N * 8;     // N*64
    float* den1 = acc1 + (size_t)N * 64;    // N*8
    float* h2   = den1 + (size_t)N * 8;     // N
    float* als2 = h2   + N;                 // N
    float* ald2 = als2 + N;                 // N
    float* acc2 = ald2 + N;                 // N
    float* den2 = acc2 + N;                 // N

    k1<<<(N + 3) / 4, 256, 0, stream>>>(x, W1, as1, ad1, h1, als, ald, acc1, den1, N);
    long long t2 = (long long)E * 8;
    k2<<<(unsigned)((t2 + 255) / 256), 256, 0, stream>>>(ei, E, h1, als, ald, acc1, den1);
    k3<<<(N + 3) / 4, 256, 0, stream>>>(acc1, den1, b1, W2, as2, ad2, h2, als2, ald2, acc2, den2, N);
    k4<<<(E + 255) / 256, 256, 0, stream>>>(ei, E, h2, als2, ald2, acc2, den2);
    k5<<<(N + 255) / 256, 256, 0, stream>>>(acc2, den2, b2, (float*)d_out, N);
}

// Round 3
// 940.131 us; speedup vs baseline: 6.7964x; 6.7964x over previous
//
#include <hip/hip_runtime.h>
#include <math.h>

#define NEG 0.2f

__device__ __forceinline__ float lrelu(float v) { return fmaxf(v, NEG * v); }

// K1: per-node: h1 = x@W1 (64 cols), al_src/al_dst logits. One wave per node.
// (Unchanged from round 1 — passed full protocol there.)
__global__ __launch_bounds__(256) void k1(const float* __restrict__ x,
        const float* __restrict__ W1, const float* __restrict__ a_src,
        const float* __restrict__ a_dst,
        float* __restrict__ h1, float* __restrict__ als, float* __restrict__ ald, int N)
{
    __shared__ float Wl[128 * 64];
    __shared__ float xl[4][128];
    const float4* Wv = (const float4*)W1;
    float4* Wlv = (float4*)Wl;
    for (int i = threadIdx.x; i < 128 * 16; i += 256) Wlv[i] = Wv[i];

    int wave = threadIdx.x >> 6;
    int lane = threadIdx.x & 63;
    int n = blockIdx.x * 4 + wave;
    if (n < N) {
        const float4* xv = (const float4*)(x + (size_t)n * 128);
        float4* xlv = (float4*)xl[wave];
        if (lane < 32) xlv[lane] = xv[lane];
    }
    __syncthreads();
    if (n >= N) return;

    const float* xr = xl[wave];
    float sum = 0.f;
    #pragma unroll 8
    for (int k = 0; k < 128; ++k) sum = fmaf(xr[k], Wl[k * 64 + lane], sum);
    h1[(size_t)n * 64 + lane] = sum;

    float ps = sum * a_src[lane];
    float pd = sum * a_dst[lane];
    #pragma unroll
    for (int off = 1; off < 8; off <<= 1) {
        ps += __shfl_xor(ps, off, 64);
        pd += __shfl_xor(pd, off, 64);
    }
    if ((lane & 7) == 0) {
        int h = lane >> 3;
        als[n * 8 + h] = ps;
        ald[n * 8 + h] = pd;
    }
}

// KH: histogram of dst degrees.
__global__ __launch_bounds__(256) void kh(const int* __restrict__ ei, int E, int N,
                                          int* __restrict__ cnt)
{
    int e = blockIdx.x * 256 + threadIdx.x;
    if (e >= E) return;
    int d = ei[E + e];
    if ((unsigned)d < (unsigned)N) atomicAdd(&cnt[d], 1);
}

// KA: single-kernel CSR offset allocator. Block-local inclusive scan of 256
// degree counts, then ONE atomicAdd on gtotal for the block's base. Row
// storage order across blocks is arbitrary — all reads go through rowptr.
__global__ __launch_bounds__(256) void ka(const int* __restrict__ cnt,
        int* __restrict__ rowptr, int* __restrict__ cursor,
        int* __restrict__ gtotal, int N)
{
    __shared__ int s[256];
    __shared__ int base;
    int tid = threadIdx.x;
    int g = blockIdx.x * 256 + tid;
    int v = (g < N) ? cnt[g] : 0;
    s[tid] = v;
    __syncthreads();
    #pragma unroll
    for (int off = 1; off < 256; off <<= 1) {
        int t = (tid >= off) ? s[tid - off] : 0;
        __syncthreads();
        s[tid] += t;
        __syncthreads();
    }
    if (tid == 255) base = atomicAdd(gtotal, s[255]);
    __syncthreads();
    if (g < N) {
        int r = base + s[tid] - v;  // exclusive offset within global CSR pool
        rowptr[g] = r;
        cursor[g] = r;
    }
}

// KC: scatter edge srcs into CSR by dst. Write is bounds-guarded: even under
// transient bad state a wild write outside csr[] is impossible.
__global__ __launch_bounds__(256) void kc(const int* __restrict__ ei, int E, int N,
        int* __restrict__ cursor, int* __restrict__ csr)
{
    int e = blockIdx.x * 256 + threadIdx.x;
    if (e >= E) return;
    int s = ei[e];
    int d = ei[E + e];
    if ((unsigned)d >= (unsigned)N) return;
    int p = atomicAdd(&cursor[d], 1);
    if ((unsigned)p < (unsigned)E) csr[p] = s;
}

// G1: fused layer-1 edge gather + node epilogue. One wave per dst node,
// lane = output channel, head = lane>>3. Softmax max-subtraction skipped
// (shift-invariant; logits are O(10)).
__global__ __launch_bounds__(256) void g1(const int* __restrict__ csr,
        const int* __restrict__ rowptr, const int* __restrict__ cnt,
        const float* __restrict__ h1, const float* __restrict__ als,
        const float* __restrict__ ald,
        const float* __restrict__ b1, const float* __restrict__ W2,
        const float* __restrict__ a_src2, const float* __restrict__ a_dst2,
        float2* __restrict__ h2a, float* __restrict__ ald2, int N, int E)
{
    int wave = threadIdx.x >> 6, lane = threadIdx.x & 63;
    int n = blockIdx.x * 4 + wave;
    if (n >= N) return;
    int h = lane >> 3;

    float ald_h = ald[n * 8 + h];
    float hv = h1[(size_t)n * 64 + lane];
    float w = __expf(lrelu(als[n * 8 + h] + ald_h));
    float den = w;
    float acc = w * hv;

    int start = rowptr[n];
    int c = cnt[n];
    // defensive clamps — no-ops in a correct run
    if ((unsigned)start >= (unsigned)E) { start = 0; c = 0; }
    if (c < 0) c = 0;
    if (start + c > E) c = E - start;

    for (int i = 0; i < c; ++i) {
        int src = csr[start + i];
        if ((unsigned)src >= (unsigned)N) src = 0;
        float ww = __expf(lrelu(als[src * 8 + h] + ald_h));
        den += ww;
        acc = fmaf(ww, h1[(size_t)src * 64 + lane], acc);
    }

    float v = fmaxf(acc / den + b1[lane], 0.f);
    float t = v * W2[lane];
    #pragma unroll
    for (int off = 1; off < 64; off <<= 1) t += __shfl_xor(t, off, 64);
    if (lane == 0) {
        float2 p;
        p.x = t;
        p.y = t * a_src2[0];
        h2a[n] = p;
        ald2[n] = t * a_dst2[0];
    }
}

// G2: fused layer-2 edge gather + final normalize. One wave per dst node,
// lanes stride the edge list, shuffle-reduce.
__global__ __launch_bounds__(256) void g2(const int* __restrict__ csr,
        const int* __restrict__ rowptr, const int* __restrict__ cnt,
        const float2* __restrict__ h2a, const float* __restrict__ ald2,
        const float* __restrict__ b2, float* __restrict__ out, int N, int E)
{
    int wave = threadIdx.x >> 6, lane = threadIdx.x & 63;
    int n = blockIdx.x * 4 + wave;
    if (n >= N) return;

    float ad = ald2[n];
    int start = rowptr[n];
    int c = cnt[n];
    if ((unsigned)start >= (unsigned)E) { start = 0; c = 0; }
    if (c < 0) c = 0;
    if (start + c > E) c = E - start;

    float den = 0.f, acc = 0.f;
    for (int i = lane; i < c; i += 64) {
        int src = csr[start + i];
        if ((unsigned)src >= (unsigned)N) src = 0;
        float2 p = h2a[src];
        float w = __expf(lrelu(p.y + ad));
        den += w;
        acc = fmaf(w, p.x, acc);
    }
    #pragma unroll
    for (int off = 1; off < 64; off <<= 1) {
        den += __shfl_xor(den, off, 64);
        acc += __shfl_xor(acc, off, 64);
    }
    if (lane == 0) {
        float2 p = h2a[n];                       // self-loop
        float w0 = __expf(lrelu(p.y + ad));
        out[n] = (acc + w0 * p.x) / (den + w0) + b2[0];
    }
}

extern "C" void kernel_launch(void* const* d_in, const int* in_sizes, int n_in,
                              void* d_out, int out_size, void* d_ws, size_t ws_size,
                              hipStream_t stream)
{
    const float* x   = (const float*)d_in[0];
    const float* W1  = (const float*)d_in[1];
    const float* as1 = (const float*)d_in[2];
    const float* ad1 = (const float*)d_in[3];
    const float* b1  = (const float*)d_in[4];
    const float* W2  = (const float*)d_in[5];
    const float* as2 = (const float*)d_in[6];
    const float* ad2 = (const float*)d_in[7];
    const float* b2  = (const float*)d_in[8];
    const int*   ei  = (const int*)d_in[9];

    int N = in_sizes[0] / 128;
    int E = in_sizes[9] / 2;

    float* ws   = (float*)d_ws;
    float* h1   = ws;                              // 64N floats
    float* als  = h1  + (size_t)N * 64;            // 8N
    float* ald  = als + (size_t)N * 8;             // 8N
    float2* h2a = (float2*)(ald + (size_t)N * 8);  // N float2 (8B aligned)
    float* ald2 = (float*)(h2a + N);               // N
    int* ip     = (int*)(ald2 + N);
    int* cnt    = ip;                              // N
    int* gtotal = cnt + N;                         // 1 (pad to 8)
    int* rowptr = gtotal + 8;                      // N
    int* cursor = rowptr + N;                      // N
    int* csr    = cursor + N;                      // E

    // zero cnt + gtotal in one memset
    hipMemsetAsync(ip, 0, ((size_t)N + 8) * sizeof(int), stream);

    k1<<<(N + 3) / 4, 256, 0, stream>>>(x, W1, as1, ad1, h1, als, ald, N);
    kh<<<(E + 255) / 256, 256, 0, stream>>>(ei, E, N, cnt);
    ka<<<(N + 255) / 256, 256, 0, stream>>>(cnt, rowptr, cursor, gtotal, N);
    kc<<<(E + 255) / 256, 256, 0, stream>>>(ei, E, N, cursor, csr);
    g1<<<(N + 3) / 4, 256, 0, stream>>>(csr, rowptr, cnt, h1, als, ald,
                                        b1, W2, as2, ad2, h2a, ald2, N, E);
    g2<<<(N + 3) / 4, 256, 0, stream>>>(csr, rowptr, cnt, h2a, ald2, b2,
                                        (float*)d_out, N, E);
}

// Round 4
// 663.067 us; speedup vs baseline: 9.6362x; 1.4179x over previous
//
#include <hip/hip_runtime.h>
#include <math.h>

#define NEG 0.2f

__device__ __forceinline__ float lrelu(float v) { return fmaxf(v, NEG * v); }

__device__ __forceinline__ unsigned short f2bf(float f) {
    unsigned u = __float_as_uint(f);
    u = (u + 0x7fffu + ((u >> 16) & 1u)) >> 16;   // RNE
    return (unsigned short)u;
}
__device__ __forceinline__ float bf2f(unsigned short s) {
    return __uint_as_float((unsigned)s << 16);
}

// K1: h1 = x@W1 -> bf16, plus fp32-exact attention logits.
// Block = 256 threads = 4 waves; each wave computes 16 nodes (64 nodes/block).
// Lane (g = lane>>4, c = lane&15) owns nodes {4g+j} x cols {4c..4c+3}:
// per k, one ds_read_b128 of W (4 cols) + one ds_read_b128 of x^T (4 nodes)
// feeds 16 FMAs -> VALU-bound instead of LDS-bound.
__global__ __launch_bounds__(256) void k1(const float* __restrict__ x,
        const float* __restrict__ W1, const float* __restrict__ a_src,
        const float* __restrict__ a_dst,
        unsigned short* __restrict__ h1b, float* __restrict__ als,
        float* __restrict__ ald, int N)
{
    __shared__ float Wl[128 * 64];      // [k][col]
    __shared__ float xt[128][68];       // [k][node_local], pad 68 (16B-aligned rows, conflict-free b128)

    const int tid = threadIdx.x;
    const int base = blockIdx.x * 64;

    const float4* Wv = (const float4*)W1;
    float4* Wlv = (float4*)Wl;
    for (int i = tid; i < 128 * 16; i += 256) Wlv[i] = Wv[i];

    for (int idx = tid; idx < 64 * 32; idx += 256) {
        int nl = idx >> 5;
        int k4 = (idx & 31) * 4;
        int n = base + nl;
        float4 v = make_float4(0.f, 0.f, 0.f, 0.f);
        if (n < N) v = *(const float4*)&x[(size_t)n * 128 + k4];
        xt[k4 + 0][nl] = v.x;
        xt[k4 + 1][nl] = v.y;
        xt[k4 + 2][nl] = v.z;
        xt[k4 + 3][nl] = v.w;
    }
    __syncthreads();

    const int wave = tid >> 6, lane = tid & 63;
    const int g = lane >> 4, c = lane & 15;
    const int nl0 = wave * 16 + 4 * g;      // first of this lane's 4 nodes

    float acc[4][4];
    #pragma unroll
    for (int j = 0; j < 4; ++j)
        #pragma unroll
        for (int t = 0; t < 4; ++t) acc[j][t] = 0.f;

    #pragma unroll 4
    for (int k = 0; k < 128; ++k) {
        float4 wv = *(const float4*)&Wl[k * 64 + 4 * c];
        float4 xv = *(const float4*)&xt[k][nl0];
        const float xs[4] = {xv.x, xv.y, xv.z, xv.w};
        const float wsv[4] = {wv.x, wv.y, wv.z, wv.w};
        #pragma unroll
        for (int j = 0; j < 4; ++j)
            #pragma unroll
            for (int t = 0; t < 4; ++t)
                acc[j][t] = fmaf(xs[j], wsv[t], acc[j][t]);
    }

    float a_s[4], a_d[4];
    #pragma unroll
    for (int t = 0; t < 4; ++t) { a_s[t] = a_src[4 * c + t]; a_d[t] = a_dst[4 * c + t]; }

    #pragma unroll
    for (int j = 0; j < 4; ++j) {
        int n = base + nl0 + j;
        float ps = 0.f, pd = 0.f;
        #pragma unroll
        for (int t = 0; t < 4; ++t) {
            ps = fmaf(acc[j][t], a_s[t], ps);
            pd = fmaf(acc[j][t], a_d[t], pd);
        }
        ps += __shfl_xor(ps, 1, 64);    // pair (c even/odd) -> per-head sum
        pd += __shfl_xor(pd, 1, 64);
        if (n < N) {
            ushort4 hb;
            hb.x = f2bf(acc[j][0]); hb.y = f2bf(acc[j][1]);
            hb.z = f2bf(acc[j][2]); hb.w = f2bf(acc[j][3]);
            *(ushort4*)&h1b[(size_t)n * 64 + 4 * c] = hb;
            if ((c & 1) == 0) {
                als[n * 8 + (c >> 1)] = ps;
                ald[n * 8 + (c >> 1)] = pd;
            }
        }
    }
}

// KH: histogram of dst degrees.
__global__ __launch_bounds__(256) void kh(const int* __restrict__ ei, int E, int N,
                                          int* __restrict__ cnt)
{
    int e = blockIdx.x * 256 + threadIdx.x;
    if (e >= E) return;
    int d = ei[E + e];
    if ((unsigned)d < (unsigned)N) atomicAdd(&cnt[d], 1);
}

// KA: CSR offset allocator — block scan + one global atomicAdd per block.
__global__ __launch_bounds__(256) void ka(const int* __restrict__ cnt,
        int* __restrict__ rowptr, int* __restrict__ cursor,
        int* __restrict__ gtotal, int N)
{
    __shared__ int s[256];
    __shared__ int base;
    int tid = threadIdx.x;
    int g = blockIdx.x * 256 + tid;
    int v = (g < N) ? cnt[g] : 0;
    s[tid] = v;
    __syncthreads();
    #pragma unroll
    for (int off = 1; off < 256; off <<= 1) {
        int t = (tid >= off) ? s[tid - off] : 0;
        __syncthreads();
        s[tid] += t;
        __syncthreads();
    }
    if (tid == 255) base = atomicAdd(gtotal, s[255]);
    __syncthreads();
    if (g < N) {
        int r = base + s[tid] - v;
        rowptr[g] = r;
        cursor[g] = r;
    }
}

// KC: scatter edge srcs into CSR by dst (bounds-guarded).
__global__ __launch_bounds__(256) void kc(const int* __restrict__ ei, int E, int N,
        int* __restrict__ cursor, int* __restrict__ csr)
{
    int e = blockIdx.x * 256 + threadIdx.x;
    if (e >= E) return;
    int s = ei[e];
    int d = ei[E + e];
    if ((unsigned)d >= (unsigned)N) return;
    int p = atomicAdd(&cursor[d], 1);
    if ((unsigned)p < (unsigned)E) csr[p] = s;
}

// G1: fused layer-1 gather + node epilogue. One wave per dst node, lane = col.
// csr chunk cached in a lane register + __shfl broadcast; edge loop unrolled
// x4 for memory-level parallelism. h1 is bf16 (halves gather bytes).
__global__ __launch_bounds__(256) void g1(const int* __restrict__ csr,
        const int* __restrict__ rowptr, const int* __restrict__ cnt,
        const unsigned short* __restrict__ h1b, const float* __restrict__ als,
        const float* __restrict__ ald,
        const float* __restrict__ b1, const float* __restrict__ W2,
        const float* __restrict__ a_src2, const float* __restrict__ a_dst2,
        float2* __restrict__ h2a, float* __restrict__ ald2, int N, int E)
{
    int wave = threadIdx.x >> 6, lane = threadIdx.x & 63;
    int n = blockIdx.x * 4 + wave;
    if (n >= N) return;
    int h = lane >> 3;

    float ald_h = ald[n * 8 + h];
    float hv = bf2f(h1b[(size_t)n * 64 + lane]);
    float w = __expf(lrelu(als[n * 8 + h] + ald_h));
    float den = w;
    float acc = w * hv;

    int start = rowptr[n];
    int c = cnt[n];
    if ((unsigned)start >= (unsigned)E) { start = 0; c = 0; }
    if (c < 0) c = 0;
    if (start + c > E) c = E - start;

    for (int cbase = 0; cbase < c; cbase += 64) {
        int rem = c - cbase; if (rem > 64) rem = 64;
        int sv = 0;
        if (lane < rem) {
            int t = csr[start + cbase + lane];
            if ((unsigned)t < (unsigned)N) sv = t;
        }
        int i = 0;
        for (; i + 4 <= rem; i += 4) {
            int s0 = __shfl(sv, i + 0, 64);
            int s1 = __shfl(sv, i + 1, 64);
            int s2 = __shfl(sv, i + 2, 64);
            int s3 = __shfl(sv, i + 3, 64);
            float a0 = als[s0 * 8 + h];
            float a1 = als[s1 * 8 + h];
            float a2 = als[s2 * 8 + h];
            float a3 = als[s3 * 8 + h];
            unsigned short u0 = h1b[s0 * 64 + lane];
            unsigned short u1 = h1b[s1 * 64 + lane];
            unsigned short u2 = h1b[s2 * 64 + lane];
            unsigned short u3 = h1b[s3 * 64 + lane];
            float w0 = __expf(lrelu(a0 + ald_h));
            float w1 = __expf(lrelu(a1 + ald_h));
            float w2 = __expf(lrelu(a2 + ald_h));
            float w3 = __expf(lrelu(a3 + ald_h));
            den += (w0 + w1) + (w2 + w3);
            acc = fmaf(w0, bf2f(u0), acc);
            acc = fmaf(w1, bf2f(u1), acc);
            acc = fmaf(w2, bf2f(u2), acc);
            acc = fmaf(w3, bf2f(u3), acc);
        }
        for (; i < rem; ++i) {
            int s0 = __shfl(sv, i, 64);
            float a0 = als[s0 * 8 + h];
            unsigned short u0 = h1b[s0 * 64 + lane];
            float w0 = __expf(lrelu(a0 + ald_h));
            den += w0;
            acc = fmaf(w0, bf2f(u0), acc);
        }
    }

    float v = fmaxf(acc / den + b1[lane], 0.f);
    float t = v * W2[lane];
    #pragma unroll
    for (int off = 1; off < 64; off <<= 1) t += __shfl_xor(t, off, 64);
    if (lane == 0) {
        float2 p;
        p.x = t;
        p.y = t * a_src2[0];
        h2a[n] = p;
        ald2[n] = t * a_dst2[0];
    }
}

// G2: fused layer-2 gather + final normalize. Two nodes per wave (32 lanes each).
__global__ __launch_bounds__(256) void g2(const int* __restrict__ csr,
        const int* __restrict__ rowptr, const int* __restrict__ cnt,
        const float2* __restrict__ h2a, const float* __restrict__ ald2,
        const float* __restrict__ b2, float* __restrict__ out, int N, int E)
{
    int sub = threadIdx.x >> 5;          // 0..7 within block
    int l32 = threadIdx.x & 31;
    int n = blockIdx.x * 8 + sub;
    if (n >= N) return;

    float ad = ald2[n];
    int start = rowptr[n];
    int c = cnt[n];
    if ((unsigned)start >= (unsigned)E) { start = 0; c = 0; }
    if (c < 0) c = 0;
    if (start + c > E) c = E - start;

    float den = 0.f, acc = 0.f;
    for (int i = l32; i < c; i += 32) {
        int src = csr[start + i];
        if ((unsigned)src >= (unsigned)N) src = 0;
        float2 p = h2a[src];
        float w = __expf(lrelu(p.y + ad));
        den += w;
        acc = fmaf(w, p.x, acc);
    }
    #pragma unroll
    for (int off = 1; off < 32; off <<= 1) {
        den += __shfl_xor(den, off, 32);
        acc += __shfl_xor(acc, off, 32);
    }
    if (l32 == 0) {
        float2 p = h2a[n];                       // self-loop
        float w0 = __expf(lrelu(p.y + ad));
        out[n] = (acc + w0 * p.x) / (den + w0) + b2[0];
    }
}

extern "C" void kernel_launch(void* const* d_in, const int* in_sizes, int n_in,
                              void* d_out, int out_size, void* d_ws, size_t ws_size,
                              hipStream_t stream)
{
    const float* x   = (const float*)d_in[0];
    const float* W1  = (const float*)d_in[1];
    const float* as1 = (const float*)d_in[2];
    const float* ad1 = (const float*)d_in[3];
    const float* b1  = (const float*)d_in[4];
    const float* W2  = (const float*)d_in[5];
    const float* as2 = (const float*)d_in[6];
    const float* ad2 = (const float*)d_in[7];
    const float* b2  = (const float*)d_in[8];
    const int*   ei  = (const int*)d_in[9];

    int N = in_sizes[0] / 128;
    int E = in_sizes[9] / 2;

    char* wsb = (char*)d_ws;
    unsigned short* h1b = (unsigned short*)wsb;            // 64N ushorts = 128N B
    float* als  = (float*)(wsb + (size_t)128 * N);         // 8N f32
    float* ald  = als + (size_t)N * 8;                     // 8N
    float2* h2a = (float2*)(ald + (size_t)N * 8);          // N float2
    float* ald2 = (float*)(h2a + N);                       // N
    int* ip     = (int*)(ald2 + N);
    int* cnt    = ip;                                      // N
    int* gtotal = cnt + N;                                 // 1 (padded to 8)
    int* rowptr = gtotal + 8;                              // N
    int* cursor = rowptr + N;                              // N
    int* csr    = cursor + N;                              // E

    hipMemsetAsync(ip, 0, ((size_t)N + 8) * sizeof(int), stream);

    k1<<<(N + 63) / 64, 256, 0, stream>>>(x, W1, as1, ad1, h1b, als, ald, N);
    kh<<<(E + 255) / 256, 256, 0, stream>>>(ei, E, N, cnt);
    ka<<<(N + 255) / 256, 256, 0, stream>>>(cnt, rowptr, cursor, gtotal, N);
    kc<<<(E + 255) / 256, 256, 0, stream>>>(ei, E, N, cursor, csr);
    g1<<<(N + 3) / 4, 256, 0, stream>>>(csr, rowptr, cnt, h1b, als, ald,
                                        b1, W2, as2, ad2, h2a, ald2, N, E);
    g2<<<(N + 7) / 8, 256, 0, stream>>>(csr, rowptr, cnt, h2a, ald2, b2,
                                        (float*)d_out, N, E);
}

// Round 5
// 393.257 us; speedup vs baseline: 16.2475x; 1.6861x over previous
//
#include <hip/hip_runtime.h>
#include <math.h>

#define NEG 0.2f
#define CHUNK 16384

__device__ __forceinline__ float lrelu(float v) { return fmaxf(v, NEG * v); }

__device__ __forceinline__ unsigned short f2bf(float f) {
    unsigned u = __float_as_uint(f);
    u = (u + 0x7fffu + ((u >> 16) & 1u)) >> 16;   // RNE
    return (unsigned short)u;
}
__device__ __forceinline__ float bf2f(unsigned short s) {
    return __uint_as_float((unsigned)s << 16);
}

// K1: h1 = x@W1 -> bf16, plus fp32-exact attention logits. (proven in R4)
__global__ __launch_bounds__(256) void k1(const float* __restrict__ x,
        const float* __restrict__ W1, const float* __restrict__ a_src,
        const float* __restrict__ a_dst,
        unsigned short* __restrict__ h1b, float* __restrict__ als,
        float* __restrict__ ald, int N)
{
    __shared__ float Wl[128 * 64];
    __shared__ float xt[128][68];

    const int tid = threadIdx.x;
    const int base = blockIdx.x * 64;

    const float4* Wv = (const float4*)W1;
    float4* Wlv = (float4*)Wl;
    for (int i = tid; i < 128 * 16; i += 256) Wlv[i] = Wv[i];

    for (int idx = tid; idx < 64 * 32; idx += 256) {
        int nl = idx >> 5;
        int k4 = (idx & 31) * 4;
        int n = base + nl;
        float4 v = make_float4(0.f, 0.f, 0.f, 0.f);
        if (n < N) v = *(const float4*)&x[(size_t)n * 128 + k4];
        xt[k4 + 0][nl] = v.x;
        xt[k4 + 1][nl] = v.y;
        xt[k4 + 2][nl] = v.z;
        xt[k4 + 3][nl] = v.w;
    }
    __syncthreads();

    const int wave = tid >> 6, lane = tid & 63;
    const int g = lane >> 4, c = lane & 15;
    const int nl0 = wave * 16 + 4 * g;

    float acc[4][4];
    #pragma unroll
    for (int j = 0; j < 4; ++j)
        #pragma unroll
        for (int t = 0; t < 4; ++t) acc[j][t] = 0.f;

    #pragma unroll 4
    for (int k = 0; k < 128; ++k) {
        float4 wv = *(const float4*)&Wl[k * 64 + 4 * c];
        float4 xv = *(const float4*)&xt[k][nl0];
        const float xs[4] = {xv.x, xv.y, xv.z, xv.w};
        const float wsv[4] = {wv.x, wv.y, wv.z, wv.w};
        #pragma unroll
        for (int j = 0; j < 4; ++j)
            #pragma unroll
            for (int t = 0; t < 4; ++t)
                acc[j][t] = fmaf(xs[j], wsv[t], acc[j][t]);
    }

    float a_s[4], a_d[4];
    #pragma unroll
    for (int t = 0; t < 4; ++t) { a_s[t] = a_src[4 * c + t]; a_d[t] = a_dst[4 * c + t]; }

    #pragma unroll
    for (int j = 0; j < 4; ++j) {
        int n = base + nl0 + j;
        float ps = 0.f, pd = 0.f;
        #pragma unroll
        for (int t = 0; t < 4; ++t) {
            ps = fmaf(acc[j][t], a_s[t], ps);
            pd = fmaf(acc[j][t], a_d[t], pd);
        }
        ps += __shfl_xor(ps, 1, 64);
        pd += __shfl_xor(pd, 1, 64);
        if (n < N) {
            ushort4 hb;
            hb.x = f2bf(acc[j][0]); hb.y = f2bf(acc[j][1]);
            hb.z = f2bf(acc[j][2]); hb.w = f2bf(acc[j][3]);
            *(ushort4*)&h1b[(size_t)n * 64 + 4 * c] = hb;
            if ((c & 1) == 0) {
                als[n * 8 + (c >> 1)] = ps;
                ald[n * 8 + (c >> 1)] = pd;
            }
        }
    }
}

// ---------- atomic-free CSR build (P1..P4) ----------

// P1: per-chunk LDS histogram over coarse buckets (dst>>8). Each block owns
// row j of T[b*NC + j] — no global atomics.
__global__ __launch_bounds__(256) void p1(const int* __restrict__ ei, int E, int N,
        int* __restrict__ T, int NB, int NC)
{
    extern __shared__ int hist[];   // NB ints
    int tid = threadIdx.x;
    for (int b = tid; b < NB; b += 256) hist[b] = 0;
    __syncthreads();
    int base = blockIdx.x * CHUNK;
    for (int i = tid; i < CHUNK; i += 256) {
        int e = base + i;
        if (e >= E) break;
        int d = ei[E + e];
        if ((unsigned)d < (unsigned)N) atomicAdd(&hist[d >> 8], 1);
    }
    __syncthreads();
    for (int b = tid; b < NB; b += 256) T[b * NC + blockIdx.x] = hist[b];
}

// P2a: per-bucket exclusive prefix over chunks; bucket totals. One wave/bucket.
__global__ __launch_bounds__(256) void p2a(int* __restrict__ T,
        int* __restrict__ total, int NB, int NC)
{
    int wave = threadIdx.x >> 6, lane = threadIdx.x & 63;
    int b = blockIdx.x * 4 + wave;
    if (b >= NB) return;
    int run = 0;
    for (int j0 = 0; j0 < NC; j0 += 64) {
        int j = j0 + lane;
        int orig = (j < NC) ? T[b * NC + j] : 0;
        int v = orig;
        #pragma unroll
        for (int off = 1; off < 64; off <<= 1) {
            int t = __shfl_up(v, off, 64);
            if (lane >= off) v += t;
        }
        if (j < NC) T[b * NC + j] = run + v - orig;   // exclusive within bucket
        run += __shfl(v, 63, 64);
    }
    if (lane == 0) total[b] = run;
}

// P2b: exclusive scan of bucket totals -> bstart[0..NB] (bstart[NB] = sum).
__global__ __launch_bounds__(512) void p2b(const int* __restrict__ total,
        int* __restrict__ bstart, int nb)
{
    __shared__ int s[512];
    int tid = threadIdx.x;
    int run = 0;
    for (int base = 0; base < nb; base += 512) {
        int i = base + tid;
        int orig = (i < nb) ? total[i] : 0;
        s[tid] = orig;
        __syncthreads();
        #pragma unroll
        for (int off = 1; off < 512; off <<= 1) {
            int t = (tid >= off) ? s[tid - off] : 0;
            __syncthreads();
            s[tid] += t;
            __syncthreads();
        }
        if (i < nb) bstart[i] = run + s[tid] - orig;
        int tot = s[511];
        __syncthreads();
        run += tot;
    }
    if (tid == 0) bstart[nb] = run;
}

// P3: scatter edges into bucket-grouped tmp. Unique slots via LDS cursors;
// per-(chunk,bucket) writes are contiguous runs. Payload: src | dst_lo<<24.
__global__ __launch_bounds__(256) void p3(const int* __restrict__ ei, int E, int N,
        const int* __restrict__ T, const int* __restrict__ bstart,
        unsigned* __restrict__ tmp, int NB, int NC)
{
    extern __shared__ int cur[];    // NB ints
    int tid = threadIdx.x;
    int j = blockIdx.x;
    for (int b = tid; b < NB; b += 256) cur[b] = bstart[b] + T[b * NC + j];
    __syncthreads();
    int base = j * CHUNK;
    for (int i = tid; i < CHUNK; i += 256) {
        int e = base + i;
        if (e >= E) break;
        int d = ei[E + e];
        if ((unsigned)d >= (unsigned)N) continue;
        int s = ei[e];
        if ((unsigned)s >= (unsigned)N) s = 0;
        int pos = atomicAdd(&cur[d >> 8], 1);
        if ((unsigned)pos < (unsigned)E)
            tmp[pos] = (unsigned)s | ((unsigned)(d & 255) << 24);
    }
}

// P4: one block per bucket. 256-bin LDS histogram -> cnt/rowptr, then
// LDS-cursor scatter into the exact CSR slice (contiguous 32KB window).
__global__ __launch_bounds__(256) void p4(const unsigned* __restrict__ tmp,
        const int* __restrict__ bstart,
        int* __restrict__ cnt, int* __restrict__ rowptr, int* __restrict__ csr,
        int N, int E)
{
    __shared__ int hist[256];
    __shared__ int ssc[256];
    __shared__ int cur[256];
    int tid = threadIdx.x;
    int b = blockIdx.x;
    int s0 = bstart[b], s1 = bstart[b + 1];
    if (s0 < 0) s0 = 0; if (s0 > E) s0 = E;
    if (s1 < s0) s1 = s0; if (s1 > E) s1 = E;

    hist[tid] = 0;
    __syncthreads();
    for (int i = s0 + tid; i < s1; i += 256)
        atomicAdd(&hist[tmp[i] >> 24], 1);
    __syncthreads();

    int h = hist[tid];
    ssc[tid] = h;
    __syncthreads();
    #pragma unroll
    for (int off = 1; off < 256; off <<= 1) {
        int t = (tid >= off) ? ssc[tid - off] : 0;
        __syncthreads();
        ssc[tid] += t;
        __syncthreads();
    }
    int excl = ssc[tid] - h;
    int node = b * 256 + tid;
    if (node < N) {
        cnt[node] = h;
        rowptr[node] = s0 + excl;
    }
    cur[tid] = s0 + excl;
    __syncthreads();

    for (int i = s0 + tid; i < s1; i += 256) {
        unsigned v = tmp[i];
        int pos = atomicAdd(&cur[v >> 24], 1);
        if ((unsigned)pos < (unsigned)E) csr[pos] = (int)(v & 0xFFFFFFu);
    }
}

// ---------- fallback atomic build (proven R3/R4 path) ----------

__global__ __launch_bounds__(256) void kh(const int* __restrict__ ei, int E, int N,
                                          int* __restrict__ cnt)
{
    int e = blockIdx.x * 256 + threadIdx.x;
    if (e >= E) return;
    int d = ei[E + e];
    if ((unsigned)d < (unsigned)N) atomicAdd(&cnt[d], 1);
}

__global__ __launch_bounds__(256) void ka(const int* __restrict__ cnt,
        int* __restrict__ rowptr, int* __restrict__ cursor,
        int* __restrict__ gtotal, int N)
{
    __shared__ int s[256];
    __shared__ int base;
    int tid = threadIdx.x;
    int g = blockIdx.x * 256 + tid;
    int v = (g < N) ? cnt[g] : 0;
    s[tid] = v;
    __syncthreads();
    #pragma unroll
    for (int off = 1; off < 256; off <<= 1) {
        int t = (tid >= off) ? s[tid - off] : 0;
        __syncthreads();
        s[tid] += t;
        __syncthreads();
    }
    if (tid == 255) base = atomicAdd(gtotal, s[255]);
    __syncthreads();
    if (g < N) {
        int r = base + s[tid] - v;
        rowptr[g] = r;
        cursor[g] = r;
    }
}

__global__ __launch_bounds__(256) void kc(const int* __restrict__ ei, int E, int N,
        int* __restrict__ cursor, int* __restrict__ csr)
{
    int e = blockIdx.x * 256 + threadIdx.x;
    if (e >= E) return;
    int s = ei[e];
    int d = ei[E + e];
    if ((unsigned)d >= (unsigned)N) return;
    int p = atomicAdd(&cursor[d], 1);
    if ((unsigned)p < (unsigned)E) csr[p] = s;
}

// ---------- gather kernels (proven R4 path) ----------

__global__ __launch_bounds__(256) void g1(const int* __restrict__ csr,
        const int* __restrict__ rowptr, const int* __restrict__ cnt,
        const unsigned short* __restrict__ h1b, const float* __restrict__ als,
        const float* __restrict__ ald,
        const float* __restrict__ b1, const float* __restrict__ W2,
        const float* __restrict__ a_src2, const float* __restrict__ a_dst2,
        float2* __restrict__ h2a, float* __restrict__ ald2, int N, int E)
{
    int wave = threadIdx.x >> 6, lane = threadIdx.x & 63;
    int n = blockIdx.x * 4 + wave;
    if (n >= N) return;
    int h = lane >> 3;

    float ald_h = ald[n * 8 + h];
    float hv = bf2f(h1b[(size_t)n * 64 + lane]);
    float w = __expf(lrelu(als[n * 8 + h] + ald_h));
    float den = w;
    float acc = w * hv;

    int start = rowptr[n];
    int c = cnt[n];
    if ((unsigned)start >= (unsigned)E) { start = 0; c = 0; }
    if (c < 0) c = 0;
    if (start + c > E) c = E - start;

    for (int cbase = 0; cbase < c; cbase += 64) {
        int rem = c - cbase; if (rem > 64) rem = 64;
        int sv = 0;
        if (lane < rem) {
            int t = csr[start + cbase + lane];
            if ((unsigned)t < (unsigned)N) sv = t;
        }
        int i = 0;
        for (; i + 4 <= rem; i += 4) {
            int s0 = __shfl(sv, i + 0, 64);
            int s1 = __shfl(sv, i + 1, 64);
            int s2 = __shfl(sv, i + 2, 64);
            int s3 = __shfl(sv, i + 3, 64);
            float a0 = als[s0 * 8 + h];
            float a1 = als[s1 * 8 + h];
            float a2 = als[s2 * 8 + h];
            float a3 = als[s3 * 8 + h];
            unsigned short u0 = h1b[s0 * 64 + lane];
            unsigned short u1 = h1b[s1 * 64 + lane];
            unsigned short u2 = h1b[s2 * 64 + lane];
            unsigned short u3 = h1b[s3 * 64 + lane];
            float w0 = __expf(lrelu(a0 + ald_h));
            float w1 = __expf(lrelu(a1 + ald_h));
            float w2 = __expf(lrelu(a2 + ald_h));
            float w3 = __expf(lrelu(a3 + ald_h));
            den += (w0 + w1) + (w2 + w3);
            acc = fmaf(w0, bf2f(u0), acc);
            acc = fmaf(w1, bf2f(u1), acc);
            acc = fmaf(w2, bf2f(u2), acc);
            acc = fmaf(w3, bf2f(u3), acc);
        }
        for (; i < rem; ++i) {
            int s0 = __shfl(sv, i, 64);
            float a0 = als[s0 * 8 + h];
            unsigned short u0 = h1b[s0 * 64 + lane];
            float w0 = __expf(lrelu(a0 + ald_h));
            den += w0;
            acc = fmaf(w0, bf2f(u0), acc);
        }
    }

    float v = fmaxf(acc / den + b1[lane], 0.f);
    float t = v * W2[lane];
    #pragma unroll
    for (int off = 1; off < 64; off <<= 1) t += __shfl_xor(t, off, 64);
    if (lane == 0) {
        float2 p;
        p.x = t;
        p.y = t * a_src2[0];
        h2a[n] = p;
        ald2[n] = t * a_dst2[0];
    }
}

__global__ __launch_bounds__(256) void g2(const int* __restrict__ csr,
        const int* __restrict__ rowptr, const int* __restrict__ cnt,
        const float2* __restrict__ h2a, const float* __restrict__ ald2,
        const float* __restrict__ b2, float* __restrict__ out, int N, int E)
{
    int sub = threadIdx.x >> 5;
    int l32 = threadIdx.x & 31;
    int n = blockIdx.x * 8 + sub;
    if (n >= N) return;

    float ad = ald2[n];
    int start = rowptr[n];
    int c = cnt[n];
    if ((unsigned)start >= (unsigned)E) { start = 0; c = 0; }
    if (c < 0) c = 0;
    if (start + c > E) c = E - start;

    float den = 0.f, acc = 0.f;
    for (int i = l32; i < c; i += 32) {
        int src = csr[start + i];
        if ((unsigned)src >= (unsigned)N) src = 0;
        float2 p = h2a[src];
        float w = __expf(lrelu(p.y + ad));
        den += w;
        acc = fmaf(w, p.x, acc);
    }
    #pragma unroll
    for (int off = 1; off < 32; off <<= 1) {
        den += __shfl_xor(den, off, 32);
        acc += __shfl_xor(acc, off, 32);
    }
    if (l32 == 0) {
        float2 p = h2a[n];
        float w0 = __expf(lrelu(p.y + ad));
        out[n] = (acc + w0 * p.x) / (den + w0) + b2[0];
    }
}

extern "C" void kernel_launch(void* const* d_in, const int* in_sizes, int n_in,
                              void* d_out, int out_size, void* d_ws, size_t ws_size,
                              hipStream_t stream)
{
    const float* x   = (const float*)d_in[0];
    const float* W1  = (const float*)d_in[1];
    const float* as1 = (const float*)d_in[2];
    const float* ad1 = (const float*)d_in[3];
    const float* b1  = (const float*)d_in[4];
    const float* W2  = (const float*)d_in[5];
    const float* as2 = (const float*)d_in[6];
    const float* ad2 = (const float*)d_in[7];
    const float* b2  = (const float*)d_in[8];
    const int*   ei  = (const int*)d_in[9];

    int N = in_sizes[0] / 128;
    int E = in_sizes[9] / 2;
    int NB = (N + 255) >> 8;
    int NC = (E + CHUNK - 1) / CHUNK;

    char* wsb = (char*)d_ws;
    size_t off = 0;
    auto alloc = [&](size_t bytes) -> char* {
        char* p = wsb + off;
        off = (off + bytes + 255) & ~(size_t)255;
        return p;
    };

    unsigned short* h1b = (unsigned short*)alloc((size_t)N * 64 * 2);
    float* als    = (float*)alloc((size_t)N * 8 * 4);
    float* ald    = (float*)alloc((size_t)N * 8 * 4);
    float2* h2a   = (float2*)alloc((size_t)N * 8);
    float* ald2   = (float*)alloc((size_t)N * 4);
    int* cnt      = (int*)alloc((size_t)N * 4);
    int* rowptr   = (int*)alloc((size_t)N * 4);
    int* csr      = (int*)alloc((size_t)E * 4);
    size_t common = off;

    // new-path extras
    int* T        = (int*)alloc((size_t)NB * NC * 4);
    int* total    = (int*)alloc((size_t)NB * 4);
    int* bstart   = (int*)alloc((size_t)(NB + 1) * 4);
    unsigned* tmp = (unsigned*)alloc((size_t)E * 4);
    size_t need_new = off;

    k1<<<(N + 63) / 64, 256, 0, stream>>>(x, W1, as1, ad1, h1b, als, ald, N);

    if (ws_size >= need_new && NB <= 512) {
        size_t lds = (size_t)NB * 4;
        p1<<<NC, 256, lds, stream>>>(ei, E, N, T, NB, NC);
        p2a<<<(NB + 3) / 4, 256, 0, stream>>>(T, total, NB, NC);
        p2b<<<1, 512, 0, stream>>>(total, bstart, NB);
        p3<<<NC, 256, lds, stream>>>(ei, E, N, T, bstart, tmp, NB, NC);
        p4<<<NB, 256, 0, stream>>>(tmp, bstart, cnt, rowptr, csr, N, E);
    } else {
        // fallback: proven atomic path (fits in common + small extras)
        off = common;
        int* gtotal = (int*)alloc(32);
        int* cursor = (int*)alloc((size_t)N * 4);
        hipMemsetAsync(cnt, 0, (size_t)N * sizeof(int), stream);
        hipMemsetAsync(gtotal, 0, 32, stream);
        kh<<<(E + 255) / 256, 256, 0, stream>>>(ei, E, N, cnt);
        ka<<<(N + 255) / 256, 256, 0, stream>>>(cnt, rowptr, cursor, gtotal, N);
        kc<<<(E + 255) / 256, 256, 0, stream>>>(ei, E, N, cursor, csr);
    }

    g1<<<(N + 3) / 4, 256, 0, stream>>>(csr, rowptr, cnt, h1b, als, ald,
                                        b1, W2, as2, ad2, h2a, ald2, N, E);
    g2<<<(N + 7) / 8, 256, 0, stream>>>(csr, rowptr, cnt, h2a, ald2, b2,
                                        (float*)d_out, N, E);
}